// Round 11
// baseline (9555.531 us; speedup 1.0000x reference)
//
#include <hip/hip_runtime.h>

#define NB 64
#define NS 1024
#define NI 300
#define NH 512
#define L0WG 32
#define NWG 64

typedef _Float16 f16;
typedef f16 half8 __attribute__((ext_vector_type(8)));
typedef float floatx4 __attribute__((ext_vector_type(4)));
typedef unsigned long long u64;
typedef unsigned u32;
typedef u32 u32x4 __attribute__((ext_vector_type(4)));

__device__ __attribute__((aligned(64))) f16 g_X[NS][NB][320];   // x f16, K-pad 320
__device__ __attribute__((aligned(64))) f16 g_H0[4][NB][NH];    // h0 ring
__device__ __attribute__((aligned(64))) f16 g_H1[4][NB][NH];    // h1 ring
// FIXED-ADDRESS per-WG monotonic flags (warm MALL lines; R3 protocol).
// value = base + 1 (init done), base + 2 + t (step t done). +NS+1 per replay.
__device__ __attribute__((aligned(4096))) u32 g_fl0[1024];   // [0..31] used
__device__ __attribute__((aligned(4096))) u32 g_fl1[1024];   // [0..31] used

__device__ __forceinline__ float sigm(float x){ return 1.f/(1.f+__expf(-x)); }
__device__ __forceinline__ float tanh_(float x){ return 1.f - 2.f/(__expf(2.f*x)+1.f); }

__device__ __forceinline__ u32 ldc(const u32* p){
  return __hip_atomic_load(p, __ATOMIC_RELAXED, __HIP_MEMORY_SCOPE_AGENT);
}
__device__ __forceinline__ void sig(u32* p, u32 v){
  __hip_atomic_store(p, v, __ATOMIC_RELAXED, __HIP_MEMORY_SCOPE_AGENT);
}

#define STR_(x) #x
#define STR(x) STR_(x)
#define CLOAD16(dst, base, OFF) \
  asm volatile("global_load_dwordx4 %0, %1, off offset:" STR(OFF) " sc1" \
               : "=v"(dst) : "v"(base))
#define CLOADN16(dst, base, OFF) \
  asm volatile("global_load_dwordx4 %0, %1, off offset:" STR(OFF) \
               : "=v"(dst) : "v"(base))
#define CSTORE16(base, val) \
  asm volatile("global_store_dwordx4 %0, %1, off sc1" :: "v"(base), "v"(val))
#define VWAIT(N) do { asm volatile("s_waitcnt vmcnt(" STR(N) ")" ::: "memory"); \
  __builtin_amdgcn_sched_barrier(0); } while(0)
#define MFMA(acc, a, b) acc = __builtin_amdgcn_mfma_f32_16x16x32_f16(a, b, acc, 0, 0, 0)

#define HLOADS(arr, p) do { \
  CLOAD16(arr[0],  p, 0);   CLOAD16(arr[1],  p, 64);  \
  CLOAD16(arr[2],  p, 128); CLOAD16(arr[3],  p, 192); \
  CLOAD16(arr[4],  p, 256); CLOAD16(arr[5],  p, 320); \
  CLOAD16(arr[6],  p, 384); CLOAD16(arr[7],  p, 448); \
  CLOAD16(arr[8],  p, 512); CLOAD16(arr[9],  p, 576); \
  CLOAD16(arr[10], p, 640); CLOAD16(arr[11], p, 704); \
  CLOAD16(arr[12], p, 768); CLOAD16(arr[13], p, 832); \
  CLOAD16(arr[14], p, 896); CLOAD16(arr[15], p, 960); } while(0)

// wave-0-only: one vectorized RTT checks both 32-flag arrays (warm lines)
__device__ __forceinline__ void pollA2(const u32* pa, u32 ta,
                                       const u32* pb, u32 tb, int lane){
  const u32* p = nullptr; u32 tgt = 0;
  if (lane < 8)       { p = pa + lane * 4;       tgt = ta; }
  else if (lane < 16) { p = pb + (lane - 8) * 4; tgt = tb; }
  for (;;){
    bool ok = true;
    if (p){
      u32x4 v;
      asm volatile("global_load_dwordx4 %0, %1, off sc1" : "=v"(v) : "v"(p));
      asm volatile("s_waitcnt vmcnt(0)" ::: "memory");
      ok = ((int)(v[0]-tgt) >= 0) & ((int)(v[1]-tgt) >= 0) &
           ((int)(v[2]-tgt) >= 0) & ((int)(v[3]-tgt) >= 0);
    }
    if (__all(ok)) return;
    __builtin_amdgcn_s_sleep(1);
  }
}

__global__ void __launch_bounds__(256, 1) lstm_persist(
    const float* __restrict__ xin,
    const float* __restrict__ Wih0, const float* __restrict__ Whh0,
    const float* __restrict__ bih0, const float* __restrict__ bhh0,
    const float* __restrict__ Wih1, const float* __restrict__ Whh1,
    const float* __restrict__ bih1, const float* __restrict__ bhh1,
    float* __restrict__ out)
{
  // weights in LDS: unit = 16 n-rows x 40 halves (80B stride: aligned b128,
  // 2-way bank spread). L0 uses 52 units (gates g,o), L1 96 (f,g,o).
  __shared__ f16   WB[96 * 640];          // 122880 B -> 1 WG/CU
  __shared__ f16   sh_h[4][16][24];       // 3072 B
  __shared__ float sh_o[4][2][16][20];    // 10240 B

  const int wg = blockIdx.x, tid = threadIdx.x;
  const int wv = tid >> 6, lane = tid & 63, n15 = lane & 15, g4 = lane >> 4;
  const int kb = g4 * 8;
  const int mrow = wv * 16 + n15;

  const bool isL1 = (wg >= L0WG);
  const int wgi = isL1 ? wg - L0WG : wg;
  const int j0 = wgi * 16;
  const int bb = n15 * 40 + kb;           // B-fragment half-offset within unit
  const int jc = j0 + n15;
  float bi, bf, bg, bo;
  float creg[4] = {0.f, 0.f, 0.f, 0.f};

  // base from OWN flag (single-writer -> exact; identical across WGs per replay)
  const u32 base = isL1 ? ldc(&g_fl1[wgi]) : ldc(&g_fl0[wgi]);

  if (!isL1) {
    // =========================== LAYER 0 ===========================
    bi = bih0[jc] + bhh0[jc];          bf = bih0[NH + jc] + bhh0[NH + jc];
    bg = bih0[2*NH + jc] + bhh0[2*NH + jc]; bo = bih0[3*NH + jc] + bhh0[3*NH + jc];

    // x prestage: 32 timesteps per WG, f16, pad 300->320
    {
      const int b = tid >> 2, q = tid & 3;
      for (int r = 0; r < 32; ++r) {
        const int t = wgi * 32 + r;
        const float* xr = xin + ((size_t)b * NS + t) * NI;
        u64* dst = (u64*)&g_X[t][b][0];
        #pragma unroll
        for (int e = 0; e < 20; ++e) {
          const int idx = q * 20 + e;
          u64 v = 0;
          if (idx < 75) {
            const float4 f = *(const float4*)(xr + (idx << 2));
            union { f16 h[4]; u64 u; } pk;
            pk.h[0]=(f16)f.x; pk.h[1]=(f16)f.y; pk.h[2]=(f16)f.z; pk.h[3]=(f16)f.w;
            v = pk.u;
          }
          dst[idx] = v;
        }
      }
    }
    // zero h0 ring slot 3 (read at t=0)
    if (tid < 64) {
      half8 z = {};
      CSTORE16(&g_H0[3][tid][j0], z);
      CSTORE16(&g_H0[3][tid][j0 + 8], z);
    }
    // LDS weights: gates g(u=ch), o(u=26+ch)
    for (int idx = tid; idx < 52 * 16; idx += 256) {
      const int u = idx >> 4, n = idx & 15;
      const int gl = 2 + (u >= 26);
      const int ch = (u >= 26) ? u - 26 : u;
      const int grow = gl * NH + j0 + n;
      f16* dst = &WB[u * 640 + n * 40];
      for (int k = 0; k < 32; ++k) {
        const int kk = ch * 32 + k;
        float v;
        if (kk < NI) v = Wih0[(size_t)grow * NI + kk];
        else if (kk < 320) v = 0.f;
        else v = Whh0[(size_t)grow * NH + (kk - 320)];
        dst[k] = (f16)v;
      }
    }
    // VGPR weights: gates i, f
    half8 w_i[26], w_f[26];
    {
      const int gi = j0 + n15, gf = NH + j0 + n15;
      #pragma unroll
      for (int ch = 0; ch < 26; ++ch) {
        union { f16 h[8]; half8 v; } pi, pf;
        #pragma unroll
        for (int jj = 0; jj < 8; ++jj) {
          const int kk = ch * 32 + kb + jj;
          pi.h[jj] = (f16)((kk < NI) ? Wih0[(size_t)gi * NI + kk]
                     : (kk < 320) ? 0.f : Whh0[(size_t)gi * NH + (kk - 320)]);
          pf.h[jj] = (f16)((kk < NI) ? Wih0[(size_t)gf * NI + kk]
                     : (kk < 320) ? 0.f : Whh0[(size_t)gf * NH + (kk - 320)]);
        }
        w_i[ch] = pi.v; w_f[ch] = pf.v;
      }
    }
    VWAIT(0);
    __threadfence();                       // publish g_X (normal stores) once
    __syncthreads();
    if (tid == 0) sig(&g_fl0[wgi], base + 1);
    if (wv == 0) pollA2(&g_fl0[0], base + 1, &g_fl1[0], base + 1, lane);
    __syncthreads();

    half8 xa[10];
    {
      const f16* xp = &g_X[0][mrow][0] + kb;
      CLOADN16(xa[0], xp, 0);   CLOADN16(xa[1], xp, 64);
      CLOADN16(xa[2], xp, 128); CLOADN16(xa[3], xp, 192);
      CLOADN16(xa[4], xp, 256); CLOADN16(xa[5], xp, 320);
      CLOADN16(xa[6], xp, 384); CLOADN16(xa[7], xp, 448);
      CLOADN16(xa[8], xp, 512); CLOADN16(xa[9], xp, 576);
    }

    for (int t = 0; t < NS; ++t) {
      if (t > 0) {
        if (wv == 0)
          pollA2(&g_fl0[0], base + 1 + (u32)t,
                 &g_fl1[0], (t >= 4) ? base + (u32)t - 2 : base, lane);
        __syncthreads();
      }
      const f16* hp = &g_H0[(t + 3) & 3][mrow][0] + kb;
      half8 ha[16];
      HLOADS(ha, hp);
      floatx4 ai = {0,0,0,0}, af = {0,0,0,0}, ag = {0,0,0,0}, ao = {0,0,0,0};
      VWAIT(16);                 // xa ready (oldest 10); h in flight
      #pragma unroll
      for (int ci = 0; ci < 10; ++ci) {
        const half8 a = xa[ci];
        MFMA(ai, a, w_i[ci]); MFMA(af, a, w_f[ci]);
        MFMA(ag, a, *(const half8*)&WB[ci * 640 + bb]);
        MFMA(ao, a, *(const half8*)&WB[(26 + ci) * 640 + bb]);
      }
      VWAIT(8);
      #pragma unroll
      for (int ci = 10; ci < 18; ++ci) {
        const half8 a = ha[ci - 10];
        MFMA(ai, a, w_i[ci]); MFMA(af, a, w_f[ci]);
        MFMA(ag, a, *(const half8*)&WB[ci * 640 + bb]);
        MFMA(ao, a, *(const half8*)&WB[(26 + ci) * 640 + bb]);
      }
      VWAIT(0);
      #pragma unroll
      for (int ci = 18; ci < 26; ++ci) {
        const half8 a = ha[ci - 10];
        MFMA(ai, a, w_i[ci]); MFMA(af, a, w_f[ci]);
        MFMA(ag, a, *(const half8*)&WB[ci * 640 + bb]);
        MFMA(ao, a, *(const half8*)&WB[(26 + ci) * 640 + bb]);
      }
      // epilogue: per lane 4 rows (g4*4+r) x col n15 — all gates in-lane
      #pragma unroll
      for (int r = 0; r < 4; ++r) {
        const float vi = ai[r] + bi, vf = af[r] + bf;
        const float vg = ag[r] + bg, vo = ao[r] + bo;
        const float cn = sigm(vf) * creg[r] + sigm(vi) * tanh_(vg);
        const float hn = sigm(vo) * tanh_(cn);
        creg[r] = cn;
        sh_h[wv][g4 * 4 + r][n15] = (f16)hn;
      }
      asm volatile("s_waitcnt lgkmcnt(0)" ::: "memory");
      __builtin_amdgcn_sched_barrier(0);
      if (lane < 32) {
        const half8 hv = *(const half8*)&sh_h[wv][lane >> 1][(lane & 1) * 8];
        CSTORE16(&g_H0[t & 3][wv * 16 + (lane >> 1)][j0 + (lane & 1) * 8], hv);
      }
      VWAIT(0);
      __syncthreads();
      if (tid == 0) sig(&g_fl0[wgi], base + 2 + (u32)t);
      if (t + 1 < NS) {
        const f16* xp = &g_X[t + 1][mrow][0] + kb;
        CLOADN16(xa[0], xp, 0);   CLOADN16(xa[1], xp, 64);
        CLOADN16(xa[2], xp, 128); CLOADN16(xa[3], xp, 192);
        CLOADN16(xa[4], xp, 256); CLOADN16(xa[5], xp, 320);
        CLOADN16(xa[6], xp, 384); CLOADN16(xa[7], xp, 448);
        CLOADN16(xa[8], xp, 512); CLOADN16(xa[9], xp, 576);
      }
    }

  } else {
    // =========================== LAYER 1 ===========================
    bi = bih1[jc] + bhh1[jc];          bf = bih1[NH + jc] + bhh1[NH + jc];
    bg = bih1[2*NH + jc] + bhh1[2*NH + jc]; bo = bih1[3*NH + jc] + bhh1[3*NH + jc];

    if (tid < 64) {
      half8 z = {};
      CSTORE16(&g_H1[3][tid][j0], z);
      CSTORE16(&g_H1[3][tid][j0 + 8], z);
    }
    // LDS weights: gates f(u=ch), g(u=32+ch), o(u=64+ch)
    for (int idx = tid; idx < 96 * 16; idx += 256) {
      const int u = idx >> 4, n = idx & 15;
      const int gl = 1 + (u >> 5);
      const int ch = u & 31;
      const int grow = gl * NH + j0 + n;
      f16* dst = &WB[u * 640 + n * 40];
      for (int k = 0; k < 32; ++k) {
        const int kk = ch * 32 + k;
        const float v = (kk < NH) ? Wih1[(size_t)grow * NH + kk]
                                  : Whh1[(size_t)grow * NH + (kk - NH)];
        dst[k] = (f16)v;
      }
    }
    // VGPR weights: gate i
    half8 w_i1[32];
    {
      const int gi = j0 + n15;
      #pragma unroll
      for (int ch = 0; ch < 32; ++ch) {
        union { f16 h[8]; half8 v; } pk;
        #pragma unroll
        for (int jj = 0; jj < 8; ++jj) {
          const int kk = ch * 32 + kb + jj;
          pk.h[jj] = (f16)((kk < NH) ? Wih1[(size_t)gi * NH + kk]
                                     : Whh1[(size_t)gi * NH + (kk - NH)]);
        }
        w_i1[ch] = pk.v;
      }
    }
    VWAIT(0);
    __syncthreads();
    if (tid == 0) sig(&g_fl1[wgi], base + 1);
    if (wv == 0) pollA2(&g_fl0[0], base + 1, &g_fl1[0], base + 1, lane);
    __syncthreads();

    for (int t = 0; t < NS; ++t) {
      if (wv == 0) {
        pollA2(&g_fl0[0], base + 2 + (u32)t,
               &g_fl1[0], (t >= 1) ? base + 1 + (u32)t : base, lane);
      } else {
        VWAIT(0);     // drain prev-step out stores in the poll shadow
      }
      __syncthreads();
      const f16* p0 = &g_H0[t & 3][mrow][0] + kb;         // h0(t)
      const f16* p1 = &g_H1[(t + 3) & 3][mrow][0] + kb;   // h1(t-1)
      half8 ha[16], hb[16];
      HLOADS(ha, p0);
      HLOADS(hb, p1);
      floatx4 ai = {0,0,0,0}, af = {0,0,0,0}, ag = {0,0,0,0}, ao = {0,0,0,0};
      VWAIT(24);
      #pragma unroll
      for (int ci = 0; ci < 8; ++ci) {
        const half8 a = ha[ci];
        MFMA(ai, a, w_i1[ci]);
        MFMA(af, a, *(const half8*)&WB[ci * 640 + bb]);
        MFMA(ag, a, *(const half8*)&WB[(32 + ci) * 640 + bb]);
        MFMA(ao, a, *(const half8*)&WB[(64 + ci) * 640 + bb]);
      }
      VWAIT(16);
      #pragma unroll
      for (int ci = 8; ci < 16; ++ci) {
        const half8 a = ha[ci];
        MFMA(ai, a, w_i1[ci]);
        MFMA(af, a, *(const half8*)&WB[ci * 640 + bb]);
        MFMA(ag, a, *(const half8*)&WB[(32 + ci) * 640 + bb]);
        MFMA(ao, a, *(const half8*)&WB[(64 + ci) * 640 + bb]);
      }
      VWAIT(8);
      #pragma unroll
      for (int ci = 16; ci < 24; ++ci) {
        const half8 a = hb[ci - 16];
        MFMA(ai, a, w_i1[ci]);
        MFMA(af, a, *(const half8*)&WB[ci * 640 + bb]);
        MFMA(ag, a, *(const half8*)&WB[(32 + ci) * 640 + bb]);
        MFMA(ao, a, *(const half8*)&WB[(64 + ci) * 640 + bb]);
      }
      VWAIT(0);
      #pragma unroll
      for (int ci = 24; ci < 32; ++ci) {
        const half8 a = hb[ci - 16];
        MFMA(ai, a, w_i1[ci]);
        MFMA(af, a, *(const half8*)&WB[ci * 640 + bb]);
        MFMA(ag, a, *(const half8*)&WB[(32 + ci) * 640 + bb]);
        MFMA(ao, a, *(const half8*)&WB[(64 + ci) * 640 + bb]);
      }
      #pragma unroll
      for (int r = 0; r < 4; ++r) {
        const float vi = ai[r] + bi, vf = af[r] + bf;
        const float vg = ag[r] + bg, vo = ao[r] + bo;
        const float cn = sigm(vf) * creg[r] + sigm(vi) * tanh_(vg);
        const float hn = sigm(vo) * tanh_(cn);
        creg[r] = cn;
        sh_h[wv][g4 * 4 + r][n15] = (f16)hn;
        sh_o[wv][0][g4 * 4 + r][n15] = hn;
        sh_o[wv][1][g4 * 4 + r][n15] = cn;
      }
      asm volatile("s_waitcnt lgkmcnt(0)" ::: "memory");
      __builtin_amdgcn_sched_barrier(0);
      if (lane < 32) {
        const half8 hv = *(const half8*)&sh_h[wv][lane >> 1][(lane & 1) * 8];
        CSTORE16(&g_H1[t & 3][wv * 16 + (lane >> 1)][j0 + (lane & 1) * 8], hv);
      }
      VWAIT(0);                 // drain h1 only; out-stores go after sig
      __syncthreads();
      if (tid == 0) sig(&g_fl1[wgi], base + 2 + (u32)t);
      // out-stores AFTER signal; drained at next loop-top VWAIT(0) under poll.
      {
        const int orow = lane >> 2, of4 = (lane & 3) * 4;
        const int b = wv * 16 + orow;
        const float4 hv4 = *(const float4*)&sh_o[wv][0][orow][of4];
        const float4 cv4 = *(const float4*)&sh_o[wv][1][orow][of4];
        const size_t o1 = ((size_t)b * NS + t) * NH + j0 + of4;
        *(float4*)&out[o1] = hv4;
        *(float4*)&out[(size_t)NB * NS * NH + o1] = cv4;
        if (t == NS - 1) {
          const size_t o2 = 2ull * NB * NS * NH + (size_t)b * NH + j0 + of4;
          *(float4*)&out[o2] = hv4;
          *(float4*)&out[o2 + (size_t)NB * NH] = cv4;
        }
      }
    }
  }
}

extern "C" void kernel_launch(void* const* d_in, const int* in_sizes, int n_in,
                              void* d_out, int out_size, void* d_ws, size_t ws_size,
                              hipStream_t stream) {
  (void)in_sizes; (void)n_in; (void)d_ws; (void)ws_size; (void)out_size;
  lstm_persist<<<dim3(NWG), dim3(256), 0, stream>>>(
      (const float*)d_in[0],
      (const float*)d_in[1], (const float*)d_in[2],
      (const float*)d_in[3], (const float*)d_in[4],
      (const float*)d_in[5], (const float*)d_in[6],
      (const float*)d_in[7], (const float*)d_in[8],
      (float*)d_out);
}